// Round 1
// baseline (22194.408 us; speedup 1.0000x reference)
//
#include <hip/hip_runtime.h>

#define HID 32
#define SLEN 65536
#define NB 32

__device__ __forceinline__ float fast_sigmoid(float x) {
    // 1 / (1 + 2^(-x*log2e))
    float e = __builtin_amdgcn_exp2f(-1.4426950408889634f * x);
    return __builtin_amdgcn_rcpf(1.0f + e);
}

__device__ __forceinline__ float fast_tanh(float x) {
    // tanh(x) = 1 - 2/(1 + 2^(2x*log2e)); saturates correctly at +/-inf
    float e = __builtin_amdgcn_exp2f(2.8853900817779268f * x);
    return 1.0f - 2.0f * __builtin_amdgcn_rcpf(1.0f + e);
}

// One wave (64 lanes) per batch element. Lane l computes gate rows l and l+64
// (torch gate order i,f,g,o as rows 0..127 of W_*). Lane k<32 ends with i_k,g_k;
// lane 32+k with f_k,o_k; a single xor-32 shuffle pair gives every lane all four
// gates for hidden unit k = lane&31; both mirror lanes maintain c_k redundantly.
// h is broadcast through a 16-slot LDS ring (single wave -> DS pipe in-order,
// no barriers needed). Output head is computed in bulk every 16 steps.
__global__ __launch_bounds__(64) void lstm_scan_kernel(
    const float* __restrict__ x,      // (B, 1, S)
    const float* __restrict__ W_ih,   // (128, 1)
    const float* __restrict__ W_hh,   // (128, 32)
    const float* __restrict__ b_ih,   // (128,)
    const float* __restrict__ b_hh,   // (128,)
    const float* __restrict__ W_lin,  // (1, 32)
    const float* __restrict__ b_lin,  // (1,)
    float* __restrict__ out)          // (B, 1, S)
{
    const int b    = blockIdx.x;
    const int lane = threadIdx.x;          // 0..63
    const int k    = lane & 31;

    __shared__ __align__(16) float hring[16][HID];   // ring of h_t vectors

    // ---- one-time preload (off the hot loop) ----
    float w0[HID], w1[HID];
    #pragma unroll
    for (int j = 0; j < HID; ++j) {
        w0[j] = W_hh[lane * HID + j];
        w1[j] = W_hh[(lane + 64) * HID + j];
    }
    const float bias0 = b_ih[lane]      + b_hh[lane];
    const float bias1 = b_ih[lane + 64] + b_hh[lane + 64];
    const float wih0  = W_ih[lane];        // C == 1
    const float wih1  = W_ih[lane + 64];
    const float blin  = b_lin[0];

    // y bulk pass: lane l covers ring slot s = l>>2, k-range r = (l&3)*8
    const int ys = lane >> 2;
    const int yr = (lane & 3) << 3;
    float wl[8];
    #pragma unroll
    for (int j = 0; j < 8; ++j) wl[j] = W_lin[yr + j];

    // h_{-1} = 0 lives in slot 15 (consumed at t = 0)
    if (lane < 32) hring[15][k] = 0.0f;

    float c = 0.0f;
    const float* __restrict__ xb = x + (size_t)b * SLEN;
    float* __restrict__ ob = out + (size_t)b * SLEN;

    for (int t = 0; t < SLEN; ++t) {
        // issue x_t early; consumed only after the FMA chain
        const float xt = xb[t];

        // broadcast-read h_{t-1} (all lanes same addresses -> conflict-free)
        const int rs = (t + 15) & 15;
        float hv[HID];
        const float4* hp4 = (const float4*)(&hring[rs][0]);
        #pragma unroll
        for (int j = 0; j < 8; ++j) ((float4*)hv)[j] = hp4[j];

        // two 32-long dot products, 4 accumulators each to break latency chains
        float d0 = 0.f, d1 = 0.f, d2 = 0.f, d3 = 0.f;
        float e0 = 0.f, e1 = 0.f, e2 = 0.f, e3 = 0.f;
        #pragma unroll
        for (int j = 0; j < HID; j += 4) {
            d0 = fmaf(hv[j + 0], w0[j + 0], d0);
            d1 = fmaf(hv[j + 1], w0[j + 1], d1);
            d2 = fmaf(hv[j + 2], w0[j + 2], d2);
            d3 = fmaf(hv[j + 3], w0[j + 3], d3);
            e0 = fmaf(hv[j + 0], w1[j + 0], e0);
            e1 = fmaf(hv[j + 1], w1[j + 1], e1);
            e2 = fmaf(hv[j + 2], w1[j + 2], e2);
            e3 = fmaf(hv[j + 3], w1[j + 3], e3);
        }
        const float g0 = bias0 + xt * wih0 + ((d0 + d1) + (d2 + d3));
        const float g1 = bias1 + xt * wih1 + ((e0 + e1) + (e2 + e3));

        // exchange with mirror lane (k <-> k+32)
        const float p0 = __shfl_xor(g0, 32, 64);
        const float p1 = __shfl_xor(g1, 32, 64);
        const bool lo = (lane < 32);
        const float gi = lo ? g0 : p0;   // i_k
        const float gf = lo ? p0 : g0;   // f_k
        const float gg = lo ? g1 : p1;   // g_k
        const float go = lo ? p1 : g1;   // o_k

        c = fast_sigmoid(gf) * c + fast_sigmoid(gi) * fast_tanh(gg);
        const float h = fast_sigmoid(go) * fast_tanh(c);

        if (lo) hring[t & 15][k] = h;

        // bulk output head every 16 steps: y_tt = tanh(h_tt . W_lin + b_lin)
        if ((t & 15) == 15) {
            float acc = 0.f;
            #pragma unroll
            for (int j = 0; j < 8; ++j)
                acc = fmaf(hring[ys][yr + j], wl[j], acc);
            acc += __shfl_xor(acc, 1, 64);
            acc += __shfl_xor(acc, 2, 64);
            if ((lane & 3) == 0)
                ob[t - 15 + ys] = fast_tanh(acc + blin);
        }
    }
}

extern "C" void kernel_launch(void* const* d_in, const int* in_sizes, int n_in,
                              void* d_out, int out_size, void* d_ws, size_t ws_size,
                              hipStream_t stream) {
    const float* x     = (const float*)d_in[0];
    const float* W_ih  = (const float*)d_in[1];
    const float* W_hh  = (const float*)d_in[2];
    const float* b_ih  = (const float*)d_in[3];
    const float* b_hh  = (const float*)d_in[4];
    const float* W_lin = (const float*)d_in[5];
    const float* b_lin = (const float*)d_in[6];
    float* out = (float*)d_out;

    hipLaunchKernelGGL(lstm_scan_kernel, dim3(NB), dim3(64), 0, stream,
                       x, W_ih, W_hh, b_ih, b_hh, W_lin, b_lin, out);
}

// Round 7
// 17535.609 us; speedup vs baseline: 1.2657x; 1.2657x over previous
//
#include <hip/hip_runtime.h>

#define HID     32
#define SLEN    65536
#define NB      32
#define UNROLL  32
#define NBLK    (SLEN / UNROLL)
#define RSTRIDE 36   // floats per ring row: 144B = 16B-aligned

typedef float f32x2 __attribute__((ext_vector_type(2)));
typedef float f32x4 __attribute__((ext_vector_type(4)));

__device__ __forceinline__ float fast_sigmoid(float x) {
    // 1 / (1 + 2^(-x*log2e))
    float e = __builtin_amdgcn_exp2f(-1.4426950408889634f * x);
    return __builtin_amdgcn_rcpf(1.0f + e);
}
__device__ __forceinline__ float fast_tanh(float x) {
    // 1 - 2/(1 + 2^(2x*log2e)); saturates correctly
    float e = __builtin_amdgcn_exp2f(2.8853900817779268f * x);
    return 1.0f - 2.0f * __builtin_amdgcn_rcpf(1.0f + e);
}

#if __has_builtin(__builtin_elementwise_fma)
__device__ __forceinline__ f32x2 pkfma(f32x2 a, f32x2 b, f32x2 c) {
    return __builtin_elementwise_fma(a, b, c);   // -> v_pk_fma_f32 on gfx950
}
#else
__device__ __forceinline__ f32x2 pkfma(f32x2 a, f32x2 b, f32x2 c) {
    f32x2 r; r.x = fmaf(a.x, b.x, c.x); r.y = fmaf(a.y, b.y, c.y); return r;
}
#endif

// One wave per batch element. FULLY REDUNDANT gate computation: every lane
// computes ALL FOUR gate rows for hidden unit k = lane&31 (torch row order:
// i=k, f=32+k, g=64+k, o=96+k). No cross-lane exchange of any kind — the only
// cross-lane mechanism is the LDS h-ring broadcast, which round 1 validated
// on hardware. Upper 32 lanes duplicate lower (free in SIMD lockstep).
// x is double-buffered in registers a full 32-step block ahead; output head
// runs in bulk once per block. Single wave -> in-order DS pipe, no barriers.
__global__ __launch_bounds__(64, 1) void lstm_scan_kernel(
    const float* __restrict__ x,      // (B, 1, S)
    const float* __restrict__ W_ih,   // (128, 1)
    const float* __restrict__ W_hh,   // (128, 32)
    const float* __restrict__ b_ih,   // (128,)
    const float* __restrict__ b_hh,   // (128,)
    const float* __restrict__ W_lin,  // (1, 32)
    const float* __restrict__ b_lin,  // (1,)
    float* __restrict__ out)          // (B, 1, S)
{
    const int  b    = blockIdx.x;
    const int  lane = threadIdx.x;     // 0..63
    const int  k    = lane & 31;
    const bool lo   = (lane < 32);

    __shared__ __align__(16) float hlds[32 * RSTRIDE];

    // ---- one-time preload: W_hh rows i_k, f_k, g_k, o_k (128 VGPRs) ----
    f32x2 W[4][16];
    float bias[4], wih[4];
    #pragma unroll
    for (int q = 0; q < 4; ++q) {
        const int row = q * 32 + k;
        const f32x2* wr = (const f32x2*)(W_hh + row * HID);
        #pragma unroll
        for (int j = 0; j < 16; ++j) W[q][j] = wr[j];
        bias[q] = b_ih[row] + b_hh[row];
        wih[q]  = W_ih[row];
    }
    const float blin = b_lin[0];

    // y-pass: lane l covers ring slot l>>1, half (l&1)*16
    const int ys = lane >> 1;
    const int yr = (lane & 1) << 4;
    const f32x4* wlv = (const f32x4*)(W_lin + yr);
    f32x4 wl0 = wlv[0], wl1 = wlv[1], wl2 = wlv[2], wl3 = wlv[3];

    // h_{-1} = 0 lives in slot 31 (consumed at step 0 of block 0)
    if (lo) hlds[31 * RSTRIDE + k] = 0.0f;

    float c = 0.0f;
    const float* __restrict__ xb = x   + (size_t)b * SLEN;
    float* __restrict__       ob = out + (size_t)b * SLEN;

    // x double buffer: current block in xc[], next block prefetched into xn*
    f32x4 xc[8];
    {
        const f32x4* xg = (const f32x4*)xb;
        #pragma unroll
        for (int q = 0; q < 8; ++q) xc[q] = xg[q];
    }

    for (int blk = 0; blk < NBLK; ++blk) {
        const int nb_ = (blk + 1 < NBLK) ? (blk + 1) : blk;
        const f32x4* xg = (const f32x4*)(xb + nb_ * UNROLL);
        f32x4 xn0 = xg[0], xn1 = xg[1], xn2 = xg[2], xn3 = xg[3];
        f32x4 xn4 = xg[4], xn5 = xg[5], xn6 = xg[6], xn7 = xg[7];

        #pragma unroll
        for (int u = 0; u < UNROLL; ++u) {
            const int rs = (u + 31) & 31;              // slot written last step
            const f32x4* hp = (const f32x4*)(hlds + rs * RSTRIDE);
            f32x4 hq[8];
            #pragma unroll
            for (int j = 0; j < 8; ++j) hq[j] = hp[j];  // broadcast b128 reads

            const float xt = xc[u >> 2][u & 3];

            // 4 gate dots, 2 packed accumulators each (static indices only)
            f32x2 acc0[4], acc1[4];
            #pragma unroll
            for (int q = 0; q < 4; ++q) {
                acc0[q].x = fmaf(xt, wih[q], bias[q]); acc0[q].y = 0.0f;
                acc1[q].x = 0.0f;                      acc1[q].y = 0.0f;
            }
            #pragma unroll
            for (int j = 0; j < 8; ++j) {
                const f32x2 l2 = __builtin_shufflevector(hq[j], hq[j], 0, 1);
                const f32x2 h2 = __builtin_shufflevector(hq[j], hq[j], 2, 3);
                #pragma unroll
                for (int q = 0; q < 4; ++q) {
                    acc0[q] = pkfma(l2, W[q][2 * j],     acc0[q]);
                    acc1[q] = pkfma(h2, W[q][2 * j + 1], acc1[q]);
                }
            }
            float g[4];
            #pragma unroll
            for (int q = 0; q < 4; ++q) {
                const f32x2 s = acc0[q] + acc1[q];
                g[q] = s.x + s.y;
            }

            const float si = fast_sigmoid(g[0]);
            const float sf = fast_sigmoid(g[1]);
            const float tg = fast_tanh(g[2]);
            const float so = fast_sigmoid(g[3]);
            c = fmaf(sf, c, si * tg);                 // c = sig(f)c + sig(i)tanh(g)
            const float h = so * fast_tanh(c);        // valid in ALL lanes
            if (lo) hlds[u * RSTRIDE + k] = h;

        }

        // bulk output head for this block's 32 h vectors
        {
            const f32x4* yp = (const f32x4*)(hlds + ys * RSTRIDE + yr);
            f32x4 h0 = yp[0], h1 = yp[1], h2 = yp[2], h3 = yp[3];
            float acc;
            acc = h0.x * wl0.x;
            acc = fmaf(h0.y, wl0.y, acc); acc = fmaf(h0.z, wl0.z, acc); acc = fmaf(h0.w, wl0.w, acc);
            acc = fmaf(h1.x, wl1.x, acc); acc = fmaf(h1.y, wl1.y, acc);
            acc = fmaf(h1.z, wl1.z, acc); acc = fmaf(h1.w, wl1.w, acc);
            acc = fmaf(h2.x, wl2.x, acc); acc = fmaf(h2.y, wl2.y, acc);
            acc = fmaf(h2.z, wl2.z, acc); acc = fmaf(h2.w, wl2.w, acc);
            acc = fmaf(h3.x, wl3.x, acc); acc = fmaf(h3.y, wl3.y, acc);
            acc = fmaf(h3.z, wl3.z, acc); acc = fmaf(h3.w, wl3.w, acc);
            acc += __shfl_xor(acc, 1, 64);
            if ((lane & 1) == 0) ob[blk * UNROLL + ys] = fast_tanh(acc + blin);
        }

        xc[0] = xn0; xc[1] = xn1; xc[2] = xn2; xc[3] = xn3;
        xc[4] = xn4; xc[5] = xn5; xc[6] = xn6; xc[7] = xn7;
    }
}

extern "C" void kernel_launch(void* const* d_in, const int* in_sizes, int n_in,
                              void* d_out, int out_size, void* d_ws, size_t ws_size,
                              hipStream_t stream) {
    (void)d_ws; (void)ws_size; (void)in_sizes; (void)n_in; (void)out_size;
    const float* x     = (const float*)d_in[0];
    const float* W_ih  = (const float*)d_in[1];
    const float* W_hh  = (const float*)d_in[2];
    const float* b_ih  = (const float*)d_in[3];
    const float* b_hh  = (const float*)d_in[4];
    const float* W_lin = (const float*)d_in[5];
    const float* b_lin = (const float*)d_in[6];
    float* out = (float*)d_out;

    hipLaunchKernelGGL(lstm_scan_kernel, dim3(NB), dim3(64), 0, stream,
                       x, W_ih, W_hh, b_ih, b_hh, W_lin, b_lin, out);
}

// Round 9
// 14615.338 us; speedup vs baseline: 1.5186x; 1.1998x over previous
//
#include <hip/hip_runtime.h>

#define HID     32
#define SLEN    65536
#define NB      32
#define UNROLL  32
#define NBLK    (SLEN / UNROLL)
#define RSTRIDE 36   // floats per ring row: 144B = 16B-aligned

typedef float f32x2 __attribute__((ext_vector_type(2)));
typedef float f32x4 __attribute__((ext_vector_type(4)));

__device__ __forceinline__ float fast_sigmoid(float x) {
    float e = __builtin_amdgcn_exp2f(-1.4426950408889634f * x);
    return __builtin_amdgcn_rcpf(1.0f + e);
}
__device__ __forceinline__ float fast_tanh(float x) {
    float e = __builtin_amdgcn_exp2f(2.8853900817779268f * x);
    return 1.0f - 2.0f * __builtin_amdgcn_rcpf(1.0f + e);
}

#if __has_builtin(__builtin_elementwise_fma)
__device__ __forceinline__ f32x2 pkfma(f32x2 a, f32x2 b, f32x2 c) {
    return __builtin_elementwise_fma(a, b, c);   // -> v_pk_fma_f32
}
#else
__device__ __forceinline__ f32x2 pkfma(f32x2 a, f32x2 b, f32x2 c) {
    f32x2 r; r.x = fmaf(a.x, b.x, c.x); r.y = fmaf(a.y, b.y, c.y); return r;
}
#endif

// ROUND-1-VALIDATED DATAFLOW (passed, absmax 9.8e-4), accelerated.
// One wave per batch element. Lane l owns W_hh rows l and l+64 (torch order
// i,f,g,o): lanes 0-31 hold (i_k, g_k), lanes 32-63 hold (f_k, o_k), k=lane&31.
// Per step: two 32-dot products via v_pk_fma_f32 (dot code validated round 7);
// TWO independent __shfl_xor(gate,32,64) exchanges of the RAW gate sums
// (validated round 1); then ALL lanes redundantly compute all four gate
// nonlinearities and maintain the SAME c (validated rounds 1 & 7) — no
// half-owned state (rounds 2/4/5/8 all failed with half-owned c). Lower lanes
// write h to a 32-slot LDS ring. Weights = 64 VGPRs/lane so total live regs
// ~200 < 256 (round 7's 128-VGPR W forced AGPR-copy spills, VGPR_Count=104).
// x double-buffered in registers one 32-step block ahead (validated r1/r7).
// Bulk y head per block (validated round 7). Single wave -> no barriers.
__global__ __launch_bounds__(64, 1) void lstm_scan_kernel(
    const float* __restrict__ x,      // (B, 1, S)
    const float* __restrict__ W_ih,   // (128, 1)
    const float* __restrict__ W_hh,   // (128, 32)
    const float* __restrict__ b_ih,   // (128,)
    const float* __restrict__ b_hh,   // (128,)
    const float* __restrict__ W_lin,  // (1, 32)
    const float* __restrict__ b_lin,  // (1,)
    float* __restrict__ out)          // (B, 1, S)
{
    const int  b    = blockIdx.x;
    const int  lane = threadIdx.x;     // 0..63
    const int  k    = lane & 31;
    const bool lo   = (lane < 32);

    __shared__ __align__(16) float hlds[32 * RSTRIDE];

    // ---- one-time preload: W_hh rows lane, lane+64 (64 VGPRs) ----
    const f32x2* wr0 = (const f32x2*)(W_hh + lane * HID);
    const f32x2* wr1 = (const f32x2*)(W_hh + (lane + 64) * HID);
    f32x2 w0p[16], w1p[16];
    #pragma unroll
    for (int j = 0; j < 16; ++j) { w0p[j] = wr0[j]; w1p[j] = wr1[j]; }
    const float bias0 = b_ih[lane]      + b_hh[lane];
    const float bias1 = b_ih[lane + 64] + b_hh[lane + 64];
    const float wih0  = W_ih[lane];
    const float wih1  = W_ih[lane + 64];
    const float blin  = b_lin[0];

    // y-pass: lane l covers ring slot l>>1, half (l&1)*16
    const int ys = lane >> 1;
    const int yr = (lane & 1) << 4;
    const f32x4* wlv = (const f32x4*)(W_lin + yr);
    f32x4 wl0 = wlv[0], wl1 = wlv[1], wl2 = wlv[2], wl3 = wlv[3];

    // h_{-1} = 0 lives in slot 31 (consumed at step 0 of block 0)
    if (lo) hlds[31 * RSTRIDE + k] = 0.0f;

    float c = 0.0f;
    const float* __restrict__ xb = x   + (size_t)b * SLEN;
    float* __restrict__       ob = out + (size_t)b * SLEN;

    // x double buffer: current block in xc[], next block prefetched into xn*
    f32x4 xc[8];
    {
        const f32x4* xg = (const f32x4*)xb;
        #pragma unroll
        for (int q = 0; q < 8; ++q) xc[q] = xg[q];
    }

    for (int blk = 0; blk < NBLK; ++blk) {
        const int nb_ = (blk + 1 < NBLK) ? (blk + 1) : blk;
        const f32x4* xg = (const f32x4*)(xb + nb_ * UNROLL);
        f32x4 xn0 = xg[0], xn1 = xg[1], xn2 = xg[2], xn3 = xg[3];
        f32x4 xn4 = xg[4], xn5 = xg[5], xn6 = xg[6], xn7 = xg[7];

        #pragma unroll
        for (int u = 0; u < UNROLL; ++u) {
            const int rs = (u + 31) & 31;              // slot written last step
            const f32x4* hp = (const f32x4*)(hlds + rs * RSTRIDE);
            f32x4 hq[8];
            #pragma unroll
            for (int j = 0; j < 8; ++j) hq[j] = hp[j];  // broadcast b128 reads

            const float xt = xc[u >> 2][u & 3];

            // two gate dots (rows lane, lane+64), 2 packed accumulators each
            f32x2 a0 = { fmaf(xt, wih0, bias0), 0.0f }, a1 = { 0.0f, 0.0f };
            f32x2 b0 = { fmaf(xt, wih1, bias1), 0.0f }, b1 = { 0.0f, 0.0f };
            #pragma unroll
            for (int j = 0; j < 8; ++j) {
                const f32x2 l2 = __builtin_shufflevector(hq[j], hq[j], 0, 1);
                const f32x2 h2 = __builtin_shufflevector(hq[j], hq[j], 2, 3);
                a0 = pkfma(l2, w0p[2 * j],     a0);
                a1 = pkfma(h2, w0p[2 * j + 1], a1);
                b0 = pkfma(l2, w1p[2 * j],     b0);
                b1 = pkfma(h2, w1p[2 * j + 1], b1);
            }
            const f32x2 sa = a0 + a1;
            const f32x2 sb = b0 + b1;
            const float g0 = sa.x + sa.y;   // lower: i_k   upper: f_k
            const float g1 = sb.x + sb.y;   // lower: g_k   upper: o_k

            // exchange RAW gate sums with mirror lane (round-1-validated)
            const float p0 = __shfl_xor(g0, 32, 64);
            const float p1 = __shfl_xor(g1, 32, 64);
            const float gi = lo ? g0 : p0;   // i_k
            const float gf = lo ? p0 : g0;   // f_k
            const float gg = lo ? g1 : p1;   // g_k
            const float go = lo ? p1 : g1;   // o_k

            // ALL lanes redundantly maintain the same c (round-1/7-validated)
            c = fmaf(fast_sigmoid(gf), c, fast_sigmoid(gi) * fast_tanh(gg));
            const float h = fast_sigmoid(go) * fast_tanh(c);
            if (lo) hlds[u * RSTRIDE + k] = h;
        }

        // bulk output head for this block's 32 h vectors (validated round 7)
        {
            const f32x4* yp = (const f32x4*)(hlds + ys * RSTRIDE + yr);
            f32x4 h0 = yp[0], h1 = yp[1], h2 = yp[2], h3 = yp[3];
            float acc;
            acc = h0.x * wl0.x;
            acc = fmaf(h0.y, wl0.y, acc); acc = fmaf(h0.z, wl0.z, acc); acc = fmaf(h0.w, wl0.w, acc);
            acc = fmaf(h1.x, wl1.x, acc); acc = fmaf(h1.y, wl1.y, acc);
            acc = fmaf(h1.z, wl1.z, acc); acc = fmaf(h1.w, wl1.w, acc);
            acc = fmaf(h2.x, wl2.x, acc); acc = fmaf(h2.y, wl2.y, acc);
            acc = fmaf(h2.z, wl2.z, acc); acc = fmaf(h2.w, wl2.w, acc);
            acc = fmaf(h3.x, wl3.x, acc); acc = fmaf(h3.y, wl3.y, acc);
            acc = fmaf(h3.z, wl3.z, acc); acc = fmaf(h3.w, wl3.w, acc);
            acc += __shfl_xor(acc, 1, 64);
            if ((lane & 1) == 0) ob[blk * UNROLL + ys] = fast_tanh(acc + blin);
        }

        xc[0] = xn0; xc[1] = xn1; xc[2] = xn2; xc[3] = xn3;
        xc[4] = xn4; xc[5] = xn5; xc[6] = xn6; xc[7] = xn7;
    }
}

extern "C" void kernel_launch(void* const* d_in, const int* in_sizes, int n_in,
                              void* d_out, int out_size, void* d_ws, size_t ws_size,
                              hipStream_t stream) {
    (void)d_ws; (void)ws_size; (void)in_sizes; (void)n_in; (void)out_size;
    const float* x     = (const float*)d_in[0];
    const float* W_ih  = (const float*)d_in[1];
    const float* W_hh  = (const float*)d_in[2];
    const float* b_ih  = (const float*)d_in[3];
    const float* b_hh  = (const float*)d_in[4];
    const float* W_lin = (const float*)d_in[5];
    const float* b_lin = (const float*)d_in[6];
    float* out = (float*)d_out;

    hipLaunchKernelGGL(lstm_scan_kernel, dim3(NB), dim3(64), 0, stream,
                       x, W_ih, W_hh, b_ih, b_hh, W_lin, b_lin, out);
}

// Round 10
// 13296.478 us; speedup vs baseline: 1.6692x; 1.0992x over previous
//
#include <hip/hip_runtime.h>

#define HID     32
#define SLEN    65536
#define NB      32
#define UNROLL  32
#define NBLK    (SLEN / UNROLL)
#define RSTRIDE 36   // floats per ring row: 144B = 16B-aligned

typedef float    f32x2 __attribute__((ext_vector_type(2)));
typedef float    f32x4 __attribute__((ext_vector_type(4)));
typedef unsigned u32x2 __attribute__((ext_vector_type(2)));

__device__ __forceinline__ float fast_sigmoid(float x) {
    float e = __builtin_amdgcn_exp2f(-1.4426950408889634f * x);
    return __builtin_amdgcn_rcpf(1.0f + e);
}
__device__ __forceinline__ float fast_tanh(float x) {
    float e = __builtin_amdgcn_exp2f(2.8853900817779268f * x);
    return 1.0f - 2.0f * __builtin_amdgcn_rcpf(1.0f + e);
}

#if __has_builtin(__builtin_elementwise_fma)
__device__ __forceinline__ f32x2 pkfma(f32x2 a, f32x2 b, f32x2 c) {
    return __builtin_elementwise_fma(a, b, c);   // -> v_pk_fma_f32
}
#else
__device__ __forceinline__ f32x2 pkfma(f32x2 a, f32x2 b, f32x2 c) {
    f32x2 r; r.x = fmaf(a.x, b.x, c.x); r.y = fmaf(a.y, b.y, c.y); return r;
}
#endif

// Exchange halves of a wave-wide value g (lanes 0-31 own one datum, 32-63 the
// mirror datum). Returns {lower_owned_in_all_lanes, upper_owned_in_all_lanes}.
// v_permlane32_swap_b32 semantics: new VDST = [old VDST.lo | old VSRC.lo],
// new VSRC = [old VDST.hi | old VSRC.hi]; with VDST=VSRC=g both results are
// half-uniform. Bit-exact same data movement as the two-__shfl_xor fallback.
#if __has_builtin(__builtin_amdgcn_permlane32_swap)
#define HAVE_PERMLANE_SWAP 1
__device__ __forceinline__ void half_exchange(float g, bool /*lo*/, float& low_own, float& up_own) {
    u32x2 r = __builtin_amdgcn_permlane32_swap(__float_as_uint(g), __float_as_uint(g), false, false);
    low_own = __uint_as_float(r.x);
    up_own  = __uint_as_float(r.y);
}
#else
#define HAVE_PERMLANE_SWAP 0
__device__ __forceinline__ void half_exchange(float g, bool lo, float& low_own, float& up_own) {
    const float p = __shfl_xor(g, 32, 64);   // round-9-validated fallback
    low_own = lo ? g : p;
    up_own  = lo ? p : g;
}
#endif

// ROUND-9-VALIDATED DATAFLOW (passed, absmax 2.9e-3), shuffle latency removed.
// One wave per batch element. Lane l owns W_hh rows l and l+64 (torch order
// i,f,g,o): lanes 0-31 hold (i_k, g_k), lanes 32-63 hold (f_k, o_k), k=lane&31.
// Per step: two 32-dot products via v_pk_fma_f32; the RAW gate sums are
// half-exchanged (permlane32_swap builtin — 1 VALU op — replacing round 9's
// two DS-pipe __shfl_xor, ~110 cy off the serial chain); then ALL lanes
// redundantly compute all four gate nonlinearities and maintain the SAME c
// (the half-owned-c variants of rounds 2/4/5/8 all failed; never again).
// Lower lanes write h to a 32-slot LDS ring (round-1-validated broadcast).
// x double-buffered in registers one 32-step block ahead; bulk y head per
// block. Single wave -> in-order DS pipe, no barriers.
__global__ __launch_bounds__(64, 1) void lstm_scan_kernel(
    const float* __restrict__ x,      // (B, 1, S)
    const float* __restrict__ W_ih,   // (128, 1)
    const float* __restrict__ W_hh,   // (128, 32)
    const float* __restrict__ b_ih,   // (128,)
    const float* __restrict__ b_hh,   // (128,)
    const float* __restrict__ W_lin,  // (1, 32)
    const float* __restrict__ b_lin,  // (1,)
    float* __restrict__ out)          // (B, 1, S)
{
    const int  b    = blockIdx.x;
    const int  lane = threadIdx.x;     // 0..63
    const int  k    = lane & 31;
    const bool lo   = (lane < 32);

    __shared__ __align__(16) float hlds[32 * RSTRIDE];

    // ---- one-time preload: W_hh rows lane, lane+64 ----
    const f32x2* wr0 = (const f32x2*)(W_hh + lane * HID);
    const f32x2* wr1 = (const f32x2*)(W_hh + (lane + 64) * HID);
    f32x2 w0p[16], w1p[16];
    #pragma unroll
    for (int j = 0; j < 16; ++j) { w0p[j] = wr0[j]; w1p[j] = wr1[j]; }
    const float bias0 = b_ih[lane]      + b_hh[lane];
    const float bias1 = b_ih[lane + 64] + b_hh[lane + 64];
    const float wih0  = W_ih[lane];
    const float wih1  = W_ih[lane + 64];
    const float blin  = b_lin[0];

    // y-pass: lane l covers ring slot l>>1, half (l&1)*16
    const int ys = lane >> 1;
    const int yr = (lane & 1) << 4;
    const f32x4* wlv = (const f32x4*)(W_lin + yr);
    f32x4 wl0 = wlv[0], wl1 = wlv[1], wl2 = wlv[2], wl3 = wlv[3];

    // h_{-1} = 0 lives in slot 31 (consumed at step 0 of block 0)
    if (lo) hlds[31 * RSTRIDE + k] = 0.0f;

    float c = 0.0f;
    const float* __restrict__ xb = x   + (size_t)b * SLEN;
    float* __restrict__       ob = out + (size_t)b * SLEN;

    // x double buffer: current block in xc[], next block prefetched into xn*
    f32x4 xc[8];
    {
        const f32x4* xg = (const f32x4*)xb;
        #pragma unroll
        for (int q = 0; q < 8; ++q) xc[q] = xg[q];
    }

    for (int blk = 0; blk < NBLK; ++blk) {
        const int nb_ = (blk + 1 < NBLK) ? (blk + 1) : blk;
        const f32x4* xg = (const f32x4*)(xb + nb_ * UNROLL);
        f32x4 xn0 = xg[0], xn1 = xg[1], xn2 = xg[2], xn3 = xg[3];
        f32x4 xn4 = xg[4], xn5 = xg[5], xn6 = xg[6], xn7 = xg[7];

        #pragma unroll
        for (int u = 0; u < UNROLL; ++u) {
            const int rs = (u + 31) & 31;              // slot written last step
            const f32x4* hp = (const f32x4*)(hlds + rs * RSTRIDE);
            f32x4 hq[8];
            #pragma unroll
            for (int j = 0; j < 8; ++j) hq[j] = hp[j];  // broadcast b128 reads

            const float xt = xc[u >> 2][u & 3];

            // two gate dots (rows lane, lane+64), 2 packed accumulators each
            f32x2 a0 = { fmaf(xt, wih0, bias0), 0.0f }, a1 = { 0.0f, 0.0f };
            f32x2 b0 = { fmaf(xt, wih1, bias1), 0.0f }, b1 = { 0.0f, 0.0f };
            #pragma unroll
            for (int j = 0; j < 8; ++j) {
                const f32x2 l2 = __builtin_shufflevector(hq[j], hq[j], 0, 1);
                const f32x2 h2 = __builtin_shufflevector(hq[j], hq[j], 2, 3);
                a0 = pkfma(l2, w0p[2 * j],     a0);
                a1 = pkfma(h2, w0p[2 * j + 1], a1);
                b0 = pkfma(l2, w1p[2 * j],     b0);
                b1 = pkfma(h2, w1p[2 * j + 1], b1);
            }
            const f32x2 sa = a0 + a1;
            const f32x2 sb = b0 + b1;
            const float g0 = sa.x + sa.y;   // lower: i_k   upper: f_k
            const float g1 = sb.x + sb.y;   // lower: g_k   upper: o_k

            // half-exchange the RAW gate sums (bit-exact vs round 9's shuffles)
            float gi, gf, gg, go;
            half_exchange(g0, lo, gi, gf);   // i owned by lower, f by upper
            half_exchange(g1, lo, gg, go);   // g owned by lower, o by upper

            // ALL lanes redundantly maintain the same c (round-1/7/9-validated)
            c = fmaf(fast_sigmoid(gf), c, fast_sigmoid(gi) * fast_tanh(gg));
            const float h = fast_sigmoid(go) * fast_tanh(c);
            if (lo) hlds[u * RSTRIDE + k] = h;
        }

        // bulk output head for this block's 32 h vectors (validated round 7)
        {
            const f32x4* yp = (const f32x4*)(hlds + ys * RSTRIDE + yr);
            f32x4 h0 = yp[0], h1 = yp[1], h2 = yp[2], h3 = yp[3];
            float acc;
            acc = h0.x * wl0.x;
            acc = fmaf(h0.y, wl0.y, acc); acc = fmaf(h0.z, wl0.z, acc); acc = fmaf(h0.w, wl0.w, acc);
            acc = fmaf(h1.x, wl1.x, acc); acc = fmaf(h1.y, wl1.y, acc);
            acc = fmaf(h1.z, wl1.z, acc); acc = fmaf(h1.w, wl1.w, acc);
            acc = fmaf(h2.x, wl2.x, acc); acc = fmaf(h2.y, wl2.y, acc);
            acc = fmaf(h2.z, wl2.z, acc); acc = fmaf(h2.w, wl2.w, acc);
            acc = fmaf(h3.x, wl3.x, acc); acc = fmaf(h3.y, wl3.y, acc);
            acc = fmaf(h3.z, wl3.z, acc); acc = fmaf(h3.w, wl3.w, acc);
            acc += __shfl_xor(acc, 1, 64);
            if ((lane & 1) == 0) ob[blk * UNROLL + ys] = fast_tanh(acc + blin);
        }

        xc[0] = xn0; xc[1] = xn1; xc[2] = xn2; xc[3] = xn3;
        xc[4] = xn4; xc[5] = xn5; xc[6] = xn6; xc[7] = xn7;
    }
}

extern "C" void kernel_launch(void* const* d_in, const int* in_sizes, int n_in,
                              void* d_out, int out_size, void* d_ws, size_t ws_size,
                              hipStream_t stream) {
    (void)d_ws; (void)ws_size; (void)in_sizes; (void)n_in; (void)out_size;
    const float* x     = (const float*)d_in[0];
    const float* W_ih  = (const float*)d_in[1];
    const float* W_hh  = (const float*)d_in[2];
    const float* b_ih  = (const float*)d_in[3];
    const float* b_hh  = (const float*)d_in[4];
    const float* W_lin = (const float*)d_in[5];
    const float* b_lin = (const float*)d_in[6];
    float* out = (float*)d_out;

    hipLaunchKernelGGL(lstm_scan_kernel, dim3(NB), dim3(64), 0, stream,
                       x, W_ih, W_hh, b_ih, b_hh, W_lin, b_lin, out);
}